// Round 4
// baseline (407.884 us; speedup 1.0000x reference)
//
#include <hip/hip_runtime.h>

#define B_   2
#define S_   2048
#define HID_ 2048
#define NH_  16
#define HD_  128
#define MAXTOK_ 2048

typedef float  f32x4  __attribute__((ext_vector_type(4)));
typedef __bf16 bf16x8 __attribute__((ext_vector_type(8)));
typedef unsigned short u16x8 __attribute__((ext_vector_type(8)));

__device__ __forceinline__ unsigned short f2bf(float f) {
  union { float fv; unsigned u; } v; v.fv = f;
  unsigned r = v.u + 0x7FFFu + ((v.u >> 16) & 1u);  // RNE
  return (unsigned short)(r >> 16);
}
__device__ __forceinline__ float bf2f(unsigned short h) {
  union { unsigned u; float fv; } v; v.u = ((unsigned)h) << 16;
  return v.fv;
}

// async global->LDS, 16B per lane (GEMM staging only; LDS dst must be contiguous)
__device__ __forceinline__ void gload16(const void* g, void* lds) {
  __builtin_amdgcn_global_load_lds(
      (const __attribute__((address_space(1))) void*)g,
      (__attribute__((address_space(3))) void*)lds, 16, 0, 0);
}

// ---------------- fused cast fp32 -> bf16 for hidden + 4 weights ----------------
#define H4_ (B_ * S_ * HID_ / 4)
#define W4_ (HID_ * HID_ / 4)
__global__ void cast_all(const float* __restrict__ h,  const float* __restrict__ wq,
                         const float* __restrict__ wk, const float* __restrict__ wv,
                         const float* __restrict__ wo,
                         unsigned short* __restrict__ xb,  unsigned short* __restrict__ wqb,
                         unsigned short* __restrict__ wkb, unsigned short* __restrict__ wvb,
                         unsigned short* __restrict__ wob) {
  const int total = H4_ + 4 * W4_;
  int i = blockIdx.x * blockDim.x + threadIdx.x;
  int stride = gridDim.x * blockDim.x;
  for (; i < total; i += stride) {
    const float* src; unsigned short* dst; int j;
    if (i < H4_) { src = h; dst = xb; j = i; }
    else {
      int k = i - H4_, wsel = k >> 20;  // W4_ = 2^20
      j = k & (W4_ - 1);
      src = (wsel == 0) ? wq : (wsel == 1) ? wk : (wsel == 2) ? wv : wo;
      dst = (wsel == 0) ? wqb : (wsel == 1) ? wkb : (wsel == 2) ? wvb : wob;
    }
    float4 v = ((const float4*)src)[j];
    ushort4 o;
    o.x = f2bf(v.x); o.y = f2bf(v.y); o.z = f2bf(v.z); o.w = f2bf(v.w);
    ((ushort4*)dst)[j] = o;
  }
}

// ---------------- fused QKV projection: 256x192 tile, BK=64, 4-phase/K-tile ----------------
// Verified round 3: 106 us, MfmaUtil 40%, SQ_LDS_BANK_CONFLICT = 0. Unchanged.
#define QKV_STG(gp, lp, rb) gload16((gp) + (size_t)(rb) * 2048, (lp) + (rb) * 64)

#define QKV_LOADA(Q) do { \
  _Pragma("unroll") \
  for (int mi_ = 0; mi_ < 2; ++mi_) { \
    const char* rp_ = (const char*)Acur + (size_t)((wm + (Q) * 32 + mi_ * 16 + rowq) * 128); \
    af[mi_][0] = *(const bf16x8*)(rp_ + cb0); \
    af[mi_][1] = *(const bf16x8*)(rp_ + cb1); \
  } } while (0)

#define QKV_LOADB() do { \
  _Pragma("unroll") \
  for (int ni_ = 0; ni_ < 3; ++ni_) { \
    const char* rp_ = (const char*)Bcur + (size_t)((wn + ni_ * 16 + rowq) * 128); \
    bfr[ni_][0] = *(const bf16x8*)(rp_ + cb0); \
    bfr[ni_][1] = *(const bf16x8*)(rp_ + cb1); \
  } } while (0)

#define QKV_MFMA(Q) do { \
  _Pragma("unroll") \
  for (int mi_ = 0; mi_ < 2; ++mi_) { \
    _Pragma("unroll") \
    for (int ni_ = 0; ni_ < 3; ++ni_) { \
      f32x4 c_ = acc[(Q) * 2 + mi_][ni_]; \
      c_ = __builtin_amdgcn_mfma_f32_16x16x32_bf16(af[mi_][0], bfr[ni_][0], c_, 0, 0, 0); \
      c_ = __builtin_amdgcn_mfma_f32_16x16x32_bf16(af[mi_][1], bfr[ni_][1], c_, 0, 0, 0); \
      acc[(Q) * 2 + mi_][ni_] = c_; \
    } } } while (0)

#define QKV_BAR    asm volatile("s_barrier" ::: "memory")
#define QKV_VMC4   asm volatile("s_waitcnt vmcnt(4)" ::: "memory")
#define QKV_VMC2   asm volatile("s_waitcnt vmcnt(2)" ::: "memory")
#define QKV_VMC0   asm volatile("s_waitcnt vmcnt(0)" ::: "memory")

__global__ __launch_bounds__(512, 2)
void gemm_qkv(const unsigned short* __restrict__ A,
              const unsigned short* __restrict__ Bw,
              unsigned short* __restrict__ Qb,
              unsigned short* __restrict__ Kb,
              unsigned short* __restrict__ Vtmp) {
  const int K = HID_;       // 2048
  const int NT = K / 64;    // 32 K-tiles
  __shared__ __align__(16) unsigned short As[2][256 * 64];
  __shared__ __align__(16) unsigned short Bs[2][192 * 64];

  const int tid = threadIdx.x, lane = tid & 63, w = tid >> 6;
  const int n0 = blockIdx.x * 192, m0 = blockIdx.y * 256;
  const int wm = (w >> 2) * 128, wn = (w & 3) * 48;
  const int rowq = lane & 15, klane = lane >> 4;
  const int sw  = (rowq & 7) << 4;
  const int cb0 = (klane * 16) ^ sw;          // ks=0 (slots 0..3)
  const int cb1 = ((klane + 4) * 16) ^ sw;    // ks=1 (slots 4..7)
  const int srow = tid >> 3;                  // 0..63
  const int dc8  = (tid & 7) * 8;             // linear lds col (elements)
  const int scol = (((tid & 7) * 16) ^ ((srow & 7) << 4)) >> 1;  // global col (elems)

  const unsigned short* Ag = A  + (size_t)(m0 + srow) * K + scol;
  const unsigned short* Bg = Bw + (size_t)(n0 + srow) * K + scol;

  f32x4 acc[8][3];
#pragma unroll
  for (int i = 0; i < 8; ++i)
#pragma unroll
    for (int j = 0; j < 3; ++j)
#pragma unroll
      for (int r = 0; r < 4; ++r) acc[i][j][r] = 0.f;

  bf16x8 af[2][2], bfr[3][2];

  {
    unsigned short* Al = (unsigned short*)&As[0][0] + srow * 64 + dc8;
    unsigned short* Bl = (unsigned short*)&Bs[0][0] + srow * 64 + dc8;
    QKV_STG(Bg, Bl, 0); QKV_STG(Bg, Bl, 64); QKV_STG(Bg, Bl, 128);
    QKV_STG(Ag, Al, 0); QKV_STG(Ag, Al, 128);
    QKV_STG(Ag, Al, 64); QKV_STG(Ag, Al, 192);
  }
  QKV_VMC2;   // oldest 5 (B0,B1,B2,A0,A2) landed
  QKV_BAR;

  const unsigned short* Acur = &As[0][0];
  const unsigned short* Bcur = &Bs[0][0];
  unsigned short* Anx = (unsigned short*)&As[1][0];
  unsigned short* Bnx = (unsigned short*)&Bs[1][0];

  for (int t = 0; t < NT - 1; ++t) {
    const int kn = (t + 1) * 64;
    const unsigned short* Agk = Ag + kn;
    const unsigned short* Bgk = Bg + kn;
    unsigned short* Al = Anx + srow * 64 + dc8;
    unsigned short* Bl = Bnx + srow * 64 + dc8;

    QKV_LOADA(0); QKV_LOADB();
    QKV_STG(Bgk, Bl, 0); QKV_STG(Bgk, Bl, 64);
    QKV_BAR;
    __builtin_amdgcn_s_setprio(1); QKV_MFMA(0); __builtin_amdgcn_s_setprio(0);
    QKV_BAR;
    QKV_LOADA(1);
    QKV_STG(Bgk, Bl, 128); QKV_STG(Agk, Al, 0);
    QKV_BAR;
    __builtin_amdgcn_s_setprio(1); QKV_MFMA(1); __builtin_amdgcn_s_setprio(0);
    QKV_VMC4;
    QKV_BAR;
    QKV_LOADA(2);
    QKV_STG(Agk, Al, 128); QKV_STG(Agk, Al, 64);
    QKV_BAR;
    __builtin_amdgcn_s_setprio(1); QKV_MFMA(2); __builtin_amdgcn_s_setprio(0);
    QKV_BAR;
    QKV_LOADA(3);
    QKV_STG(Agk, Al, 192);
    QKV_BAR;
    __builtin_amdgcn_s_setprio(1); QKV_MFMA(3); __builtin_amdgcn_s_setprio(0);
    QKV_VMC2;
    QKV_BAR;

    { const unsigned short* tp = Acur; Acur = Anx; Anx = (unsigned short*)tp; }
    { const unsigned short* tp = Bcur; Bcur = Bnx; Bnx = (unsigned short*)tp; }
  }

  QKV_LOADA(0); QKV_LOADB();
  QKV_BAR;
  __builtin_amdgcn_s_setprio(1); QKV_MFMA(0); __builtin_amdgcn_s_setprio(0);
  QKV_BAR;
  QKV_LOADA(1);
  QKV_BAR;
  __builtin_amdgcn_s_setprio(1); QKV_MFMA(1); __builtin_amdgcn_s_setprio(0);
  QKV_VMC0;
  QKV_BAR;
  QKV_LOADA(2);
  QKV_BAR;
  __builtin_amdgcn_s_setprio(1); QKV_MFMA(2); __builtin_amdgcn_s_setprio(0);
  QKV_BAR;
  QKV_LOADA(3);
  __builtin_amdgcn_s_setprio(1); QKV_MFMA(3); __builtin_amdgcn_s_setprio(0);

  const int lr0 = klane * 4;
#pragma unroll
  for (int mi = 0; mi < 8; ++mi)
#pragma unroll
    for (int ni = 0; ni < 3; ++ni)
#pragma unroll
      for (int r = 0; r < 4; ++r) {
        int r_ = m0 + wm + mi * 16 + lr0 + r;
        int c_ = n0 + wn + ni * 16 + rowq;
        float v = acc[mi][ni][r];
        int b = r_ >> 11, s = r_ & 2047;
        int proj = c_ >> 11, cin = c_ & 2047;
        if (proj == 2) {
          Vtmp[(size_t)(b * S_ + s) * HID_ + cin] = f2bf(v);
        } else {
          int hh = cin >> 7, d = cin & 127;
          unsigned short* dst = (proj == 0) ? Qb : Kb;
          dst[(((size_t)(b * NH_ + hh) * S_ + s) * HD_) + d] = f2bf(v);
        }
      }
}

// ---------------- output projection: 256x128 tile, BK=64, 4-phase/K-tile ----------------
// Same verified 8-phase/swizzle structure as gemm_qkv, adapted: BN=128 (2 B
// staging blocks), grid (16,16) = 256 blocks = EXACTLY 1 round at 1 block/CU
// (96 KiB LDS). 8 waves 2Mx4N, per-wave 128x32 = acc[8][2]. 6 loads/tile:
// order B0,B1 | A0,A2 | A1 | A3; need-by ph0={B0,B1,A0,A2} (oldest 4 ->
// vmcnt(2) at tile boundary), ph2={A1,A3} (vmcnt(4) end-ph1). fp32 epilogue.
#define OUT_LOADB() do { \
  _Pragma("unroll") \
  for (int ni_ = 0; ni_ < 2; ++ni_) { \
    const char* rp_ = (const char*)Bcur + (size_t)((wn + ni_ * 16 + rowq) * 128); \
    bfr[ni_][0] = *(const bf16x8*)(rp_ + cb0); \
    bfr[ni_][1] = *(const bf16x8*)(rp_ + cb1); \
  } } while (0)

#define OUT_MFMA(Q) do { \
  _Pragma("unroll") \
  for (int mi_ = 0; mi_ < 2; ++mi_) { \
    _Pragma("unroll") \
    for (int ni_ = 0; ni_ < 2; ++ni_) { \
      f32x4 c_ = acc[(Q) * 2 + mi_][ni_]; \
      c_ = __builtin_amdgcn_mfma_f32_16x16x32_bf16(af[mi_][0], bfr[ni_][0], c_, 0, 0, 0); \
      c_ = __builtin_amdgcn_mfma_f32_16x16x32_bf16(af[mi_][1], bfr[ni_][1], c_, 0, 0, 0); \
      acc[(Q) * 2 + mi_][ni_] = c_; \
    } } } while (0)

__global__ __launch_bounds__(512, 2)
void gemm_out(const unsigned short* __restrict__ A,
              const unsigned short* __restrict__ Bw,
              float* __restrict__ Cout) {
  const int K = HID_, N = HID_;
  const int NT = K / 64;    // 32
  __shared__ __align__(16) unsigned short As[2][256 * 64];
  __shared__ __align__(16) unsigned short Bs[2][128 * 64];

  const int tid = threadIdx.x, lane = tid & 63, w = tid >> 6;
  const int n0 = blockIdx.x * 128, m0 = blockIdx.y * 256;
  const int wm = (w >> 2) * 128, wn = (w & 3) * 32;
  const int rowq = lane & 15, klane = lane >> 4;
  const int sw  = (rowq & 7) << 4;
  const int cb0 = (klane * 16) ^ sw;
  const int cb1 = ((klane + 4) * 16) ^ sw;
  const int srow = tid >> 3;
  const int dc8  = (tid & 7) * 8;
  const int scol = (((tid & 7) * 16) ^ ((srow & 7) << 4)) >> 1;

  const unsigned short* Ag = A  + (size_t)(m0 + srow) * K + scol;
  const unsigned short* Bg = Bw + (size_t)(n0 + srow) * K + scol;

  f32x4 acc[8][2];
#pragma unroll
  for (int i = 0; i < 8; ++i)
#pragma unroll
    for (int j = 0; j < 2; ++j)
#pragma unroll
      for (int r = 0; r < 4; ++r) acc[i][j][r] = 0.f;

  bf16x8 af[2][2], bfr[2][2];

  // prologue: B0,B1 | A0,A2 | A1,A3
  {
    unsigned short* Al = (unsigned short*)&As[0][0] + srow * 64 + dc8;
    unsigned short* Bl = (unsigned short*)&Bs[0][0] + srow * 64 + dc8;
    QKV_STG(Bg, Bl, 0); QKV_STG(Bg, Bl, 64);
    QKV_STG(Ag, Al, 0); QKV_STG(Ag, Al, 128);
    QKV_STG(Ag, Al, 64); QKV_STG(Ag, Al, 192);
  }
  QKV_VMC2;   // oldest 4 (B0,B1,A0,A2) landed
  QKV_BAR;

  const unsigned short* Acur = &As[0][0];
  const unsigned short* Bcur = &Bs[0][0];
  unsigned short* Anx = (unsigned short*)&As[1][0];
  unsigned short* Bnx = (unsigned short*)&Bs[1][0];

  for (int t = 0; t < NT - 1; ++t) {
    const int kn = (t + 1) * 64;
    const unsigned short* Agk = Ag + kn;
    const unsigned short* Bgk = Bg + kn;
    unsigned short* Al = Anx + srow * 64 + dc8;
    unsigned short* Bl = Bnx + srow * 64 + dc8;

    // ph0: q0 -- stage B0',B1'
    QKV_LOADA(0); OUT_LOADB();
    QKV_STG(Bgk, Bl, 0); QKV_STG(Bgk, Bl, 64);
    QKV_BAR;
    __builtin_amdgcn_s_setprio(1); OUT_MFMA(0); __builtin_amdgcn_s_setprio(0);
    QKV_BAR;
    // ph1: q1 -- stage A0',A2'; wait A1,A3 (cur)
    QKV_LOADA(1);
    QKV_STG(Agk, Al, 0); QKV_STG(Agk, Al, 128);
    QKV_BAR;
    __builtin_amdgcn_s_setprio(1); OUT_MFMA(1); __builtin_amdgcn_s_setprio(0);
    QKV_VMC4;   // outstanding: A1,A3,B0',B1',A0',A2' -> oldest 2 (A1,A3) land
    QKV_BAR;
    // ph2: q2 -- stage A1'
    QKV_LOADA(2);
    QKV_STG(Agk, Al, 64);
    QKV_BAR;
    __builtin_amdgcn_s_setprio(1); OUT_MFMA(2); __builtin_amdgcn_s_setprio(0);
    QKV_BAR;
    // ph3: q3 -- stage A3'; wait next tile's first 4
    QKV_LOADA(3);
    QKV_STG(Agk, Al, 192);
    QKV_BAR;
    __builtin_amdgcn_s_setprio(1); OUT_MFMA(3); __builtin_amdgcn_s_setprio(0);
    QKV_VMC2;   // oldest 4 of 6 (B0',B1',A0',A2') landed for next ph0
    QKV_BAR;

    { const unsigned short* tp = Acur; Acur = Anx; Anx = (unsigned short*)tp; }
    { const unsigned short* tp = Bcur; Bcur = Bnx; Bnx = (unsigned short*)tp; }
  }

  // tail (outstanding at entry: A1,A3)
  QKV_LOADA(0); OUT_LOADB();
  QKV_BAR;
  __builtin_amdgcn_s_setprio(1); OUT_MFMA(0); __builtin_amdgcn_s_setprio(0);
  QKV_BAR;
  QKV_LOADA(1);
  QKV_BAR;
  __builtin_amdgcn_s_setprio(1); OUT_MFMA(1); __builtin_amdgcn_s_setprio(0);
  QKV_VMC0;
  QKV_BAR;
  QKV_LOADA(2);
  QKV_BAR;
  __builtin_amdgcn_s_setprio(1); OUT_MFMA(2); __builtin_amdgcn_s_setprio(0);
  QKV_BAR;
  QKV_LOADA(3);
  __builtin_amdgcn_s_setprio(1); OUT_MFMA(3); __builtin_amdgcn_s_setprio(0);

  const int lr0 = klane * 4;
#pragma unroll
  for (int mi = 0; mi < 8; ++mi)
#pragma unroll
    for (int ni = 0; ni < 2; ++ni)
#pragma unroll
      for (int r = 0; r < 4; ++r) {
        int r_ = m0 + wm + mi * 16 + lr0 + r;
        int c_ = n0 + wn + ni * 16 + rowq;
        Cout[(size_t)r_ * N + c_] = acc[mi][ni][r];
      }
}

// ---------------- RoPE: table precompute + vectorized apply ----------------
__global__ void rope_table(float2* __restrict__ tbl) {
  int i = blockIdx.x * blockDim.x + threadIdx.x;  // p*64 + d
  if (i >= MAXTOK_ * 64) return;
  int p = i >> 6, d = i & 63;
  float f = __expf(-(float)d * (9.210340371976184f / 64.f));  // 10000^(-d/64)
  float sn, cs;
  __sincosf((float)p * f, &sn, &cs);
  tbl[i] = make_float2(cs, sn);
}

// Vectorized: one thread per 8 consecutive d in [0,64); 16B loads/stores for
// both rotation halves of Q and K (was 2B scalar -> ~2.5x memory tax, G13).
#define QSCALE_ 0.12751744f
__global__ __launch_bounds__(256)
void rope_apply(unsigned short* __restrict__ Qb, unsigned short* __restrict__ Kb,
                const int* __restrict__ pos_ids, const float2* __restrict__ tbl) {
  int i = blockIdx.x * blockDim.x + threadIdx.x;  // bhs*8 + t8
  int t8 = i & 7, bhs = i >> 3;
  int s = bhs & (S_ - 1);
  int b = bhs >> 15;  // NH_*S_ = 32768
  int d0 = t8 * 8;
  int p = pos_ids[b * S_ + s];
  const float2* tp = tbl + p * 64 + d0;
  float cs[8], sn[8];
#pragma unroll
  for (int j = 0; j < 8; ++j) { float2 c2 = tp[j]; cs[j] = c2.x; sn[j] = c2.y; }
  size_t base = (size_t)bhs * HD_ + d0;
  {
    u16x8 x1 = *(const u16x8*)(Qb + base);
    u16x8 x2 = *(const u16x8*)(Qb + base + 64);
    u16x8 o1, o2;
#pragma unroll
    for (int j = 0; j < 8; ++j) {
      float a = bf2f(x1[j]), bb = bf2f(x2[j]);
      o1[j] = f2bf((a * cs[j] - bb * sn[j]) * QSCALE_);
      o2[j] = f2bf((bb * cs[j] + a * sn[j]) * QSCALE_);
    }
    *(u16x8*)(Qb + base) = o1;
    *(u16x8*)(Qb + base + 64) = o2;
  }
  {
    u16x8 x1 = *(const u16x8*)(Kb + base);
    u16x8 x2 = *(const u16x8*)(Kb + base + 64);
    u16x8 o1, o2;
#pragma unroll
    for (int j = 0; j < 8; ++j) {
      float a = bf2f(x1[j]), bb = bf2f(x2[j]);
      o1[j] = f2bf(a * cs[j] - bb * sn[j]);
      o2[j] = f2bf(bb * cs[j] + a * sn[j]);
    }
    *(u16x8*)(Kb + base) = o1;
    *(u16x8*)(Kb + base + 64) = o2;
  }
}

// ---------------- transpose V: (B,S,HID) bf16 -> (B,NH,HD,S) bf16 ----------------
// Vectorized: 16B global reads -> b128 LDS writes (pad 72 shorts = 144B rows,
// 16B-aligned); read phase: lanes span dl (conflict-free column gather),
// 8 scalar LDS reads -> one 16B global write.
__global__ __launch_bounds__(256)
void transpose_v(const unsigned short* __restrict__ Vin,
                 unsigned short* __restrict__ Vt) {
  __shared__ __align__(16) unsigned short t[64 * 72];
  const int s0 = blockIdx.x * 64, d0 = blockIdx.y * 64, bh = blockIdx.z;
  const int b = bh >> 4, h = bh & 15;
  const int tid = threadIdx.x;
#pragma unroll
  for (int it = 0; it < 2; ++it) {
    int chunk = it * 256 + tid;          // 512 chunks of 8 elems
    int sl = chunk >> 3, dc = (chunk & 7) * 8;
    u16x8 v = *(const u16x8*)&Vin[(size_t)(b * S_ + s0 + sl) * HID_ + h * HD_ + d0 + dc];
    *(u16x8*)&t[sl * 72 + dc] = v;
  }
  __syncthreads();
#pragma unroll
  for (int it = 0; it < 2; ++it) {
    int lin = it * 256 + tid;
    int dl = lin & 63, sq = (lin >> 6) * 8;  // lanes span dl -> banks spread
    u16x8 v;
#pragma unroll
    for (int j = 0; j < 8; ++j) v[j] = t[(sq + j) * 72 + dl];
    *(u16x8*)&Vt[((size_t)bh * HD_ + d0 + dl) * S_ + s0 + sq] = v;
  }
}

// ---------------- fused causal flash attention (v5) ----------------
#define KS_LD 136   // 64x128 K tile, padded (16B-aligned rows, 2-way bank aliasing)
#define VS_LD 72    // 128x64 V^T tile, padded
#define PS_LD 72    // 16x64 P tile per wave, padded (b128-aligned; Ps writes ~4-way)
__global__ __launch_bounds__(256, 2)
void attn_fused(const unsigned short* __restrict__ Qb,
                const unsigned short* __restrict__ Kb,
                const unsigned short* __restrict__ Vt,
                unsigned short* __restrict__ Ob) {
  __shared__ __align__(16) unsigned short Ks[64 * KS_LD];
  __shared__ __align__(16) unsigned short Vts[128 * VS_LD];
  __shared__ __align__(16) unsigned short Ps[4 * 16 * PS_LD];

  const int tid = threadIdx.x, lane = tid & 63, w = tid >> 6;
  const int bh = blockIdx.x;                    // fast dim: spreads heads across XCDs
  const int qt = (gridDim.y - 1) - blockIdx.y;  // descending: longest blocks first (LPT)
  const int q0 = qt * 64;
  const int b = bh >> 4, h = bh & 15;
  const int rowq = lane & 15;
  const int koff = (lane >> 4) * 8;
  const int lr0 = (lane >> 4) * 4;
  const size_t qkbase = (size_t)bh * (S_ * HD_);
  const size_t vbase  = (size_t)bh * (HD_ * S_);

  bf16x8 qf0, qf1, qf2, qf3;
  {
    const unsigned short* qrow = Qb + qkbase + (size_t)(q0 + w * 16 + rowq) * HD_;
    qf0 = *(const bf16x8*)(qrow + 0 * 32 + koff);
    qf1 = *(const bf16x8*)(qrow + 1 * 32 + koff);
    qf2 = *(const bf16x8*)(qrow + 2 * 32 + koff);
    qf3 = *(const bf16x8*)(qrow + 3 * 32 + koff);
  }

  const int krow = tid >> 4, kcol = (tid & 15) * 8;  // K: 16 rows/pass
  const int vrow = tid >> 3, vcol = (tid & 7) * 8;   // V^T: 32 rows/pass
  const unsigned short* kptr = Kb + qkbase + (size_t)krow * HD_ + kcol;
  const unsigned short* vptr = Vt + vbase + (size_t)vrow * S_ + vcol;

  f32x4 oacc[8];
  for (int i = 0; i < 8; ++i)
    for (int r = 0; r < 4; ++r) oacc[i][r] = 0.f;
  float m_r[4] = {-3e38f, -3e38f, -3e38f, -3e38f};
  float l_r[4] = {0.f, 0.f, 0.f, 0.f};

  const int nkt = qt + 1;

  float4 k0, k1, k2, k3, v0, v1, v2, v3;
  k0 = *(const float4*)(kptr + 0 * 16 * HD_);
  k1 = *(const float4*)(kptr + 1 * 16 * HD_);
  k2 = *(const float4*)(kptr + 2 * 16 * HD_);
  k3 = *(const float4*)(kptr + 3 * 16 * HD_);
  v0 = *(const float4*)(vptr + 0 * 32 * S_);
  v1 = *(const float4*)(vptr + 1 * 32 * S_);
  v2 = *(const float4*)(vptr + 2 * 32 * S_);
  v3 = *(const float4*)(vptr + 3 * 32 * S_);

  for (int kt = 0; kt < nkt; ++kt) {
    __syncthreads();  // previous tile's readers done
    *(float4*)&Ks[(krow + 0 * 16) * KS_LD + kcol] = k0;
    *(float4*)&Ks[(krow + 1 * 16) * KS_LD + kcol] = k1;
    *(float4*)&Ks[(krow + 2 * 16) * KS_LD + kcol] = k2;
    *(float4*)&Ks[(krow + 3 * 16) * KS_LD + kcol] = k3;
    *(float4*)&Vts[(vrow + 0 * 32) * VS_LD + vcol] = v0;
    *(float4*)&Vts[(vrow + 1 * 32) * VS_LD + vcol] = v1;
    *(float4*)&Vts[(vrow + 2 * 32) * VS_LD + vcol] = v2;
    *(float4*)&Vts[(vrow + 3 * 32) * VS_LD + vcol] = v3;
    if (kt + 1 < nkt) {
      const unsigned short* kp = kptr + (size_t)(kt + 1) * 64 * HD_;
      k0 = *(const float4*)(kp + 0 * 16 * HD_);
      k1 = *(const float4*)(kp + 1 * 16 * HD_);
      k2 = *(const float4*)(kp + 2 * 16 * HD_);
      k3 = *(const float4*)(kp + 3 * 16 * HD_);
    }
    __syncthreads();

    f32x4 sacc[4];
    for (int n = 0; n < 4; ++n)
      for (int r = 0; r < 4; ++r) sacc[n][r] = 0.f;
#pragma unroll
    for (int n = 0; n < 4; ++n) {
      const unsigned short* krow_p = &Ks[(n * 16 + rowq) * KS_LD + koff];
      sacc[n] = __builtin_amdgcn_mfma_f32_16x16x32_bf16(qf0, *(const bf16x8*)(krow_p + 0 * 32), sacc[n], 0, 0, 0);
      sacc[n] = __builtin_amdgcn_mfma_f32_16x16x32_bf16(qf1, *(const bf16x8*)(krow_p + 1 * 32), sacc[n], 0, 0, 0);
      sacc[n] = __builtin_amdgcn_mfma_f32_16x16x32_bf16(qf2, *(const bf16x8*)(krow_p + 2 * 32), sacc[n], 0, 0, 0);
      sacc[n] = __builtin_amdgcn_mfma_f32_16x16x32_bf16(qf3, *(const bf16x8*)(krow_p + 3 * 32), sacc[n], 0, 0, 0);
    }

    float tmax[4] = {-3e38f, -3e38f, -3e38f, -3e38f};
    if (kt == qt) {
      for (int n = 0; n < 4; ++n) {
        int col = n * 16 + rowq;
        for (int r = 0; r < 4; ++r) {
          int row = w * 16 + lr0 + r;
          float x = (col <= row) ? sacc[n][r] : -1e30f;
          sacc[n][r] = x;
          tmax[r] = fmaxf(tmax[r], x);
        }
      }
    } else {
      for (int n = 0; n < 4; ++n)
        for (int r = 0; r < 4; ++r)
          tmax[r] = fmaxf(tmax[r], sacc[n][r]);
    }
    for (int off = 1; off < 16; off <<= 1)
      for (int r = 0; r < 4; ++r) tmax[r] = fmaxf(tmax[r], __shfl_xor(tmax[r], off));
    float alpha[4];
    for (int r = 0; r < 4; ++r) {
      float mn = fmaxf(m_r[r], tmax[r]);
      alpha[r] = __builtin_amdgcn_exp2f(m_r[r] - mn);
      m_r[r] = mn;
    }
    float rs[4] = {0.f, 0.f, 0.f, 0.f};
    for (int n = 0; n < 4; ++n)
      for (int r = 0; r < 4; ++r) {
        float p = __builtin_amdgcn_exp2f(sacc[n][r] - m_r[r]);
        sacc[n][r] = p;
        rs[r] += p;
      }
    for (int off = 1; off < 16; off <<= 1)
      for (int r = 0; r < 4; ++r) rs[r] += __shfl_xor(rs[r], off);
    for (int r = 0; r < 4; ++r) l_r[r] = l_r[r] * alpha[r] + rs[r];
    for (int nd = 0; nd < 8; ++nd)
      for (int r = 0; r < 4; ++r) oacc[nd][r] *= alpha[r];

    if (kt + 1 < nkt) {
      const unsigned short* vp = vptr + (size_t)(kt + 1) * 64;
      v0 = *(const float4*)(vp + 0 * 32 * S_);
      v1 = *(const float4*)(vp + 1 * 32 * S_);
      v2 = *(const float4*)(vp + 2 * 32 * S_);
      v3 = *(const float4*)(vp + 3 * 32 * S_);
    }

    unsigned short* pw = &Ps[w * 16 * PS_LD];
    for (int n = 0; n < 4; ++n)
      for (int r = 0; r < 4; ++r)
        pw[(lr0 + r) * PS_LD + n * 16 + rowq] = f2bf(sacc[n][r]);

#pragma unroll
    for (int t2 = 0; t2 < 2; ++t2) {
      bf16x8 pa = *(const bf16x8*)&pw[rowq * PS_LD + t2 * 32 + koff];
      for (int nd = 0; nd < 8; ++nd) {
        bf16x8 vb = *(const bf16x8*)&Vts[(nd * 16 + rowq) * VS_LD + t2 * 32 + koff];
        oacc[nd] = __builtin_amdgcn_mfma_f32_16x16x32_bf16(pa, vb, oacc[nd], 0, 0, 0);
      }
    }
  }

  float linv[4];
  for (int r = 0; r < 4; ++r) linv[r] = __builtin_amdgcn_rcpf(l_r[r]);
  for (int nd = 0; nd < 8; ++nd) {
    int col = h * HD_ + nd * 16 + rowq;
    for (int r = 0; r < 4; ++r) {
      int row = q0 + w * 16 + lr0 + r;
      Ob[(size_t)(b * S_ + row) * HID_ + col] = f2bf(oacc[nd][r] * linv[r]);
    }
  }
}

// ---------------- launcher ----------------
extern "C" void kernel_launch(void* const* d_in, const int* in_sizes, int n_in,
                              void* d_out, int out_size, void* d_ws, size_t ws_size,
                              hipStream_t stream) {
  (void)in_sizes; (void)n_in; (void)out_size; (void)ws_size;
  const float* hidden = (const float*)d_in[0];
  // d_in[1] = attention_mask (causal; reproduced analytically)
  const int* pos = (const int*)d_in[2];
  const float* Wq = (const float*)d_in[3];
  const float* Wk = (const float*)d_in[4];
  const float* Wv = (const float*)d_in[5];
  const float* Wo = (const float*)d_in[6];
  float* out = (float*)d_out;

  char* ws = (char*)d_ws;
  unsigned short* Xb   = (unsigned short*)(ws);               // 16 MB  (B,S,HID) bf16
  unsigned short* Wqb  = (unsigned short*)(ws + 16777216);    // 8 MB  Wq -- Wqb/Wkb/Wvb contiguous:
  unsigned short* Wkb  = (unsigned short*)(ws + 25165824);    // 8 MB  Wk -- one (6144,2048) QKV weight
  unsigned short* Wvb  = (unsigned short*)(ws + 33554432);    // 8 MB  Wv
  unsigned short* Wob  = (unsigned short*)(ws + 41943040);    // 8 MB
  unsigned short* Qb   = (unsigned short*)(ws + 50331648);    // 16 MB (B,NH,S,HD)
  unsigned short* Kb   = (unsigned short*)(ws + 67108864);    // 16 MB
  unsigned short* Vtmp = (unsigned short*)(ws + 83886080);    // 16 MB (B,S,HID)
  unsigned short* Vtb  = (unsigned short*)(ws + 100663296);   // 16 MB (B,NH,HD,S)
  unsigned short* Ob   = Xb;          // Xb dead after QKV GEMM
  float2* tbl          = (float2*)ws; // RoPE table also lives in dead Xb region (1 MB)

  cast_all<<<2048, 256, 0, stream>>>(hidden, Wq, Wk, Wv, Wo, Xb, Wqb, Wkb, Wvb, Wob);

  // fused QKV: C (4096 x 6144) = X (4096x2048) * Wqkv^T, 256x192 tiles
  dim3 gq(3 * HID_ / 192, (B_ * S_) / 256);  // (32, 16) = 512 blocks = exactly 2 rounds
  gemm_qkv<<<gq, 512, 0, stream>>>(Xb, Wqb, Qb, Kb, Vtmp);

  rope_table<<<(MAXTOK_ * 64) / 256, 256, 0, stream>>>(tbl);
  rope_apply<<<(B_ * NH_ * S_ * 8) / 256, 256, 0, stream>>>(Qb, Kb, pos, tbl);

  dim3 tg(S_ / 64, HD_ / 64, B_ * NH_);  // (32, 2, 32)
  transpose_v<<<tg, 256, 0, stream>>>(Vtmp, Vtb);

  dim3 ag(B_ * NH_, S_ / 64);  // bh fast, qt slow (descending inside kernel)
  attn_fused<<<ag, 256, 0, stream>>>(Qb, Kb, Vtb, Ob);

  dim3 go(HID_ / 128, (B_ * S_) / 256);  // (16, 16) = 256 blocks = exactly 1 round
  gemm_out<<<go, 512, 0, stream>>>(Ob, Wob, out);
}

// Round 5
// 399.049 us; speedup vs baseline: 1.0221x; 1.0221x over previous
//
#include <hip/hip_runtime.h>

#define B_   2
#define S_   2048
#define HID_ 2048
#define NH_  16
#define HD_  128
#define MAXTOK_ 2048

typedef float  f32x4  __attribute__((ext_vector_type(4)));
typedef __bf16 bf16x8 __attribute__((ext_vector_type(8)));
typedef unsigned short u16x8 __attribute__((ext_vector_type(8)));

__device__ __forceinline__ unsigned short f2bf(float f) {
  union { float fv; unsigned u; } v; v.fv = f;
  unsigned r = v.u + 0x7FFFu + ((v.u >> 16) & 1u);  // RNE
  return (unsigned short)(r >> 16);
}
__device__ __forceinline__ float bf2f(unsigned short h) {
  union { unsigned u; float fv; } v; v.u = ((unsigned)h) << 16;
  return v.fv;
}

// async global->LDS, 16B per lane (GEMM staging only; LDS dst must be contiguous)
__device__ __forceinline__ void gload16(const void* g, void* lds) {
  __builtin_amdgcn_global_load_lds(
      (const __attribute__((address_space(1))) void*)g,
      (__attribute__((address_space(3))) void*)lds, 16, 0, 0);
}

// ---------------- fused cast fp32 -> bf16 for hidden + 4 weights ----------------
#define H4_ (B_ * S_ * HID_ / 4)
#define W4_ (HID_ * HID_ / 4)
__global__ void cast_all(const float* __restrict__ h,  const float* __restrict__ wq,
                         const float* __restrict__ wk, const float* __restrict__ wv,
                         const float* __restrict__ wo,
                         unsigned short* __restrict__ xb,  unsigned short* __restrict__ wqb,
                         unsigned short* __restrict__ wkb, unsigned short* __restrict__ wvb,
                         unsigned short* __restrict__ wob) {
  const int total = H4_ + 4 * W4_;
  int i = blockIdx.x * blockDim.x + threadIdx.x;
  int stride = gridDim.x * blockDim.x;
  for (; i < total; i += stride) {
    const float* src; unsigned short* dst; int j;
    if (i < H4_) { src = h; dst = xb; j = i; }
    else {
      int k = i - H4_, wsel = k >> 20;  // W4_ = 2^20
      j = k & (W4_ - 1);
      src = (wsel == 0) ? wq : (wsel == 1) ? wk : (wsel == 2) ? wv : wo;
      dst = (wsel == 0) ? wqb : (wsel == 1) ? wkb : (wsel == 2) ? wvb : wob;
    }
    float4 v = ((const float4*)src)[j];
    ushort4 o;
    o.x = f2bf(v.x); o.y = f2bf(v.y); o.z = f2bf(v.z); o.w = f2bf(v.w);
    ((ushort4*)dst)[j] = o;
  }
}

// ---------------- fused QKV projection: 256x192 tile, BK=64, 2-phase/K-tile ----------------
// Round-4 postmortem: MfmaUtil 40% with LDS (704 cyc/tile/CU) and MFMA (466)
// both below actual (~1165) -> barrier/phase overhead is the residual.
// 4 phases -> 2 phases per K-tile: 8 barriers -> 4, waits re-derived.
//  phA: read A rows [wm,wm+64) + all B; stage {B0,B1,B2,A0,A2}; 24 MFMA;
//       vmcnt(5)  (outstanding 7 -> oldest 2 = A1,A3 of CURRENT tile land,
//                  needed by phB's ds_reads)
//  phB: read A rows [wm+64,wm+128); stage {A1,A3}; 24 MFMA;
//       vmcnt(2)  (outstanding 7 -> oldest 5 = next tile's phA set lands)
// Swizzle (verified r2/r3: SQ_LDS_BANK_CONFLICT=0) unchanged:
// byte slot' = slot ^ (row&7), linear LDS dst + pre-swizzled global col.
#define QKV_STG(gp, lp, rb) gload16((gp) + (size_t)(rb) * 2048, (lp) + (rb) * 64)

#define QKV_LOADA2(H) do { \
  _Pragma("unroll") \
  for (int mi_ = 0; mi_ < 4; ++mi_) { \
    const char* rp_ = (const char*)Acur + (size_t)((wm + (H) * 64 + mi_ * 16 + rowq) * 128); \
    af[mi_][0] = *(const bf16x8*)(rp_ + cb0); \
    af[mi_][1] = *(const bf16x8*)(rp_ + cb1); \
  } } while (0)

#define QKV_LOADB() do { \
  _Pragma("unroll") \
  for (int ni_ = 0; ni_ < 3; ++ni_) { \
    const char* rp_ = (const char*)Bcur + (size_t)((wn + ni_ * 16 + rowq) * 128); \
    bfr[ni_][0] = *(const bf16x8*)(rp_ + cb0); \
    bfr[ni_][1] = *(const bf16x8*)(rp_ + cb1); \
  } } while (0)

#define QKV_MFMA2(H) do { \
  _Pragma("unroll") \
  for (int mi_ = 0; mi_ < 4; ++mi_) { \
    _Pragma("unroll") \
    for (int ni_ = 0; ni_ < 3; ++ni_) { \
      f32x4 c_ = acc[(H) * 4 + mi_][ni_]; \
      c_ = __builtin_amdgcn_mfma_f32_16x16x32_bf16(af[mi_][0], bfr[ni_][0], c_, 0, 0, 0); \
      c_ = __builtin_amdgcn_mfma_f32_16x16x32_bf16(af[mi_][1], bfr[ni_][1], c_, 0, 0, 0); \
      acc[(H) * 4 + mi_][ni_] = c_; \
    } } } while (0)

#define QKV_BAR    asm volatile("s_barrier" ::: "memory")
#define QKV_VMC5   asm volatile("s_waitcnt vmcnt(5)" ::: "memory")
#define QKV_VMC2   asm volatile("s_waitcnt vmcnt(2)" ::: "memory")
#define QKV_VMC0   asm volatile("s_waitcnt vmcnt(0)" ::: "memory")

__global__ __launch_bounds__(512, 2)
void gemm_qkv(const unsigned short* __restrict__ A,
              const unsigned short* __restrict__ Bw,
              unsigned short* __restrict__ Qb,
              unsigned short* __restrict__ Kb,
              unsigned short* __restrict__ Vtmp) {
  const int K = HID_;       // 2048
  const int NT = K / 64;    // 32 K-tiles
  __shared__ __align__(16) unsigned short As[2][256 * 64];
  __shared__ __align__(16) unsigned short Bs[2][192 * 64];

  const int tid = threadIdx.x, lane = tid & 63, w = tid >> 6;
  const int n0 = blockIdx.x * 192, m0 = blockIdx.y * 256;
  const int wm = (w >> 2) * 128, wn = (w & 3) * 48;
  const int rowq = lane & 15, klane = lane >> 4;
  const int sw  = (rowq & 7) << 4;
  const int cb0 = (klane * 16) ^ sw;          // ks=0 (slots 0..3)
  const int cb1 = ((klane + 4) * 16) ^ sw;    // ks=1 (slots 4..7)
  const int srow = tid >> 3;                  // 0..63
  const int dc8  = (tid & 7) * 8;             // linear lds col (elements)
  const int scol = (((tid & 7) * 16) ^ ((srow & 7) << 4)) >> 1;  // global col (elems)

  const unsigned short* Ag = A  + (size_t)(m0 + srow) * K + scol;
  const unsigned short* Bg = Bw + (size_t)(n0 + srow) * K + scol;

  f32x4 acc[8][3];
#pragma unroll
  for (int i = 0; i < 8; ++i)
#pragma unroll
    for (int j = 0; j < 3; ++j)
#pragma unroll
      for (int r = 0; r < 4; ++r) acc[i][j][r] = 0.f;

  bf16x8 af[4][2], bfr[3][2];

  // prologue: stage tile 0 into buffer 0 (steady-state issue order)
  {
    unsigned short* Al = (unsigned short*)&As[0][0] + srow * 64 + dc8;
    unsigned short* Bl = (unsigned short*)&Bs[0][0] + srow * 64 + dc8;
    QKV_STG(Bg, Bl, 0); QKV_STG(Bg, Bl, 64); QKV_STG(Bg, Bl, 128);
    QKV_STG(Ag, Al, 0); QKV_STG(Ag, Al, 128);
    QKV_STG(Ag, Al, 64); QKV_STG(Ag, Al, 192);
  }
  QKV_VMC2;   // oldest 5 (B0,B1,B2,A0,A2) landed
  QKV_BAR;

  const unsigned short* Acur = &As[0][0];
  const unsigned short* Bcur = &Bs[0][0];
  unsigned short* Anx = (unsigned short*)&As[1][0];
  unsigned short* Bnx = (unsigned short*)&Bs[1][0];

  for (int t = 0; t < NT - 1; ++t) {
    const int kn = (t + 1) * 64;
    const unsigned short* Agk = Ag + kn;
    const unsigned short* Bgk = Bg + kn;
    unsigned short* Al = Anx + srow * 64 + dc8;
    unsigned short* Bl = Bnx + srow * 64 + dc8;

    // phA: A-low half + all B; stage next tile's {B0,B1,B2,A0,A2}
    QKV_LOADA2(0); QKV_LOADB();
    QKV_STG(Bgk, Bl, 0); QKV_STG(Bgk, Bl, 64); QKV_STG(Bgk, Bl, 128);
    QKV_STG(Agk, Al, 0); QKV_STG(Agk, Al, 128);
    QKV_BAR;
    __builtin_amdgcn_s_setprio(1); QKV_MFMA2(0); __builtin_amdgcn_s_setprio(0);
    QKV_VMC5;   // outstanding 7 -> oldest 2 (A1,A3 of current tile) landed
    QKV_BAR;
    // phB: A-high half; stage next tile's {A1,A3}
    QKV_LOADA2(1);
    QKV_STG(Agk, Al, 64); QKV_STG(Agk, Al, 192);
    QKV_BAR;
    __builtin_amdgcn_s_setprio(1); QKV_MFMA2(1); __builtin_amdgcn_s_setprio(0);
    QKV_VMC2;   // outstanding 7 -> oldest 5 (next phA's set) landed
    QKV_BAR;

    { const unsigned short* tp = Acur; Acur = Anx; Anx = (unsigned short*)tp; }
    { const unsigned short* tp = Bcur; Bcur = Bnx; Bnx = (unsigned short*)tp; }
  }

  // tail tile (no staging): outstanding at entry = {A1,A3} of this tile
  QKV_LOADA2(0); QKV_LOADB();
  QKV_BAR;
  __builtin_amdgcn_s_setprio(1); QKV_MFMA2(0); __builtin_amdgcn_s_setprio(0);
  QKV_VMC0;   // drain A1,A3 before phB reads
  QKV_BAR;
  QKV_LOADA2(1);
  __builtin_amdgcn_s_setprio(1); QKV_MFMA2(1); __builtin_amdgcn_s_setprio(0);

  // epilogue scatter (C/D layout: col=lane&15, row=(lane>>4)*4+r)
  const int lr0 = klane * 4;
#pragma unroll
  for (int mi = 0; mi < 8; ++mi)
#pragma unroll
    for (int ni = 0; ni < 3; ++ni)
#pragma unroll
      for (int r = 0; r < 4; ++r) {
        int r_ = m0 + wm + mi * 16 + lr0 + r;
        int c_ = n0 + wn + ni * 16 + rowq;
        float v = acc[mi][ni][r];
        int b = r_ >> 11, s = r_ & 2047;
        int proj = c_ >> 11, cin = c_ & 2047;
        if (proj == 2) {
          Vtmp[(size_t)(b * S_ + s) * HID_ + cin] = f2bf(v);
        } else {
          int hh = cin >> 7, d = cin & 127;
          unsigned short* dst = (proj == 0) ? Qb : Kb;
          dst[(((size_t)(b * NH_ + hh) * S_ + s) * HD_) + d] = f2bf(v);
        }
      }
}

// ---------------- output projection: 256x128 tile, BK=64, 4-phase/K-tile ----------------
// (round-4 structure, unchanged this round)
#define OUT_LOADA(Q) do { \
  _Pragma("unroll") \
  for (int mi_ = 0; mi_ < 2; ++mi_) { \
    const char* rp_ = (const char*)Acur + (size_t)((wm + (Q) * 32 + mi_ * 16 + rowq) * 128); \
    af[mi_][0] = *(const bf16x8*)(rp_ + cb0); \
    af[mi_][1] = *(const bf16x8*)(rp_ + cb1); \
  } } while (0)

#define OUT_LOADB() do { \
  _Pragma("unroll") \
  for (int ni_ = 0; ni_ < 2; ++ni_) { \
    const char* rp_ = (const char*)Bcur + (size_t)((wn + ni_ * 16 + rowq) * 128); \
    bfr[ni_][0] = *(const bf16x8*)(rp_ + cb0); \
    bfr[ni_][1] = *(const bf16x8*)(rp_ + cb1); \
  } } while (0)

#define OUT_MFMA(Q) do { \
  _Pragma("unroll") \
  for (int mi_ = 0; mi_ < 2; ++mi_) { \
    _Pragma("unroll") \
    for (int ni_ = 0; ni_ < 2; ++ni_) { \
      f32x4 c_ = acc[(Q) * 2 + mi_][ni_]; \
      c_ = __builtin_amdgcn_mfma_f32_16x16x32_bf16(af[mi_][0], bfr[ni_][0], c_, 0, 0, 0); \
      c_ = __builtin_amdgcn_mfma_f32_16x16x32_bf16(af[mi_][1], bfr[ni_][1], c_, 0, 0, 0); \
      acc[(Q) * 2 + mi_][ni_] = c_; \
    } } } while (0)

#define QKV_VMC4   asm volatile("s_waitcnt vmcnt(4)" ::: "memory")

__global__ __launch_bounds__(512, 2)
void gemm_out(const unsigned short* __restrict__ A,
              const unsigned short* __restrict__ Bw,
              float* __restrict__ Cout) {
  const int K = HID_, N = HID_;
  const int NT = K / 64;    // 32
  __shared__ __align__(16) unsigned short As[2][256 * 64];
  __shared__ __align__(16) unsigned short Bs[2][128 * 64];

  const int tid = threadIdx.x, lane = tid & 63, w = tid >> 6;
  const int n0 = blockIdx.x * 128, m0 = blockIdx.y * 256;
  const int wm = (w >> 2) * 128, wn = (w & 3) * 32;
  const int rowq = lane & 15, klane = lane >> 4;
  const int sw  = (rowq & 7) << 4;
  const int cb0 = (klane * 16) ^ sw;
  const int cb1 = ((klane + 4) * 16) ^ sw;
  const int srow = tid >> 3;
  const int dc8  = (tid & 7) * 8;
  const int scol = (((tid & 7) * 16) ^ ((srow & 7) << 4)) >> 1;

  const unsigned short* Ag = A  + (size_t)(m0 + srow) * K + scol;
  const unsigned short* Bg = Bw + (size_t)(n0 + srow) * K + scol;

  f32x4 acc[8][2];
#pragma unroll
  for (int i = 0; i < 8; ++i)
#pragma unroll
    for (int j = 0; j < 2; ++j)
#pragma unroll
      for (int r = 0; r < 4; ++r) acc[i][j][r] = 0.f;

  bf16x8 af[2][2], bfr[2][2];

  {
    unsigned short* Al = (unsigned short*)&As[0][0] + srow * 64 + dc8;
    unsigned short* Bl = (unsigned short*)&Bs[0][0] + srow * 64 + dc8;
    QKV_STG(Bg, Bl, 0); QKV_STG(Bg, Bl, 64);
    QKV_STG(Ag, Al, 0); QKV_STG(Ag, Al, 128);
    QKV_STG(Ag, Al, 64); QKV_STG(Ag, Al, 192);
  }
  QKV_VMC2;   // oldest 4 (B0,B1,A0,A2) landed
  QKV_BAR;

  const unsigned short* Acur = &As[0][0];
  const unsigned short* Bcur = &Bs[0][0];
  unsigned short* Anx = (unsigned short*)&As[1][0];
  unsigned short* Bnx = (unsigned short*)&Bs[1][0];

  for (int t = 0; t < NT - 1; ++t) {
    const int kn = (t + 1) * 64;
    const unsigned short* Agk = Ag + kn;
    const unsigned short* Bgk = Bg + kn;
    unsigned short* Al = Anx + srow * 64 + dc8;
    unsigned short* Bl = Bnx + srow * 64 + dc8;

    OUT_LOADA(0); OUT_LOADB();
    QKV_STG(Bgk, Bl, 0); QKV_STG(Bgk, Bl, 64);
    QKV_BAR;
    __builtin_amdgcn_s_setprio(1); OUT_MFMA(0); __builtin_amdgcn_s_setprio(0);
    QKV_BAR;
    OUT_LOADA(1);
    QKV_STG(Agk, Al, 0); QKV_STG(Agk, Al, 128);
    QKV_BAR;
    __builtin_amdgcn_s_setprio(1); OUT_MFMA(1); __builtin_amdgcn_s_setprio(0);
    QKV_VMC4;
    QKV_BAR;
    OUT_LOADA(2);
    QKV_STG(Agk, Al, 64);
    QKV_BAR;
    __builtin_amdgcn_s_setprio(1); OUT_MFMA(2); __builtin_amdgcn_s_setprio(0);
    QKV_BAR;
    OUT_LOADA(3);
    QKV_STG(Agk, Al, 192);
    QKV_BAR;
    __builtin_amdgcn_s_setprio(1); OUT_MFMA(3); __builtin_amdgcn_s_setprio(0);
    QKV_VMC2;
    QKV_BAR;

    { const unsigned short* tp = Acur; Acur = Anx; Anx = (unsigned short*)tp; }
    { const unsigned short* tp = Bcur; Bcur = Bnx; Bnx = (unsigned short*)tp; }
  }

  OUT_LOADA(0); OUT_LOADB();
  QKV_BAR;
  __builtin_amdgcn_s_setprio(1); OUT_MFMA(0); __builtin_amdgcn_s_setprio(0);
  QKV_BAR;
  OUT_LOADA(1);
  QKV_BAR;
  __builtin_amdgcn_s_setprio(1); OUT_MFMA(1); __builtin_amdgcn_s_setprio(0);
  QKV_VMC0;
  QKV_BAR;
  OUT_LOADA(2);
  QKV_BAR;
  __builtin_amdgcn_s_setprio(1); OUT_MFMA(2); __builtin_amdgcn_s_setprio(0);
  QKV_BAR;
  OUT_LOADA(3);
  __builtin_amdgcn_s_setprio(1); OUT_MFMA(3); __builtin_amdgcn_s_setprio(0);

  const int lr0 = klane * 4;
#pragma unroll
  for (int mi = 0; mi < 8; ++mi)
#pragma unroll
    for (int ni = 0; ni < 2; ++ni)
#pragma unroll
      for (int r = 0; r < 4; ++r) {
        int r_ = m0 + wm + mi * 16 + lr0 + r;
        int c_ = n0 + wn + ni * 16 + rowq;
        Cout[(size_t)r_ * N + c_] = acc[mi][ni][r];
      }
}

// ---------------- RoPE: table precompute + vectorized apply ----------------
__global__ void rope_table(float2* __restrict__ tbl) {
  int i = blockIdx.x * blockDim.x + threadIdx.x;  // p*64 + d
  if (i >= MAXTOK_ * 64) return;
  int p = i >> 6, d = i & 63;
  float f = __expf(-(float)d * (9.210340371976184f / 64.f));  // 10000^(-d/64)
  float sn, cs;
  __sincosf((float)p * f, &sn, &cs);
  tbl[i] = make_float2(cs, sn);
}

#define QSCALE_ 0.12751744f
__global__ __launch_bounds__(256)
void rope_apply(unsigned short* __restrict__ Qb, unsigned short* __restrict__ Kb,
                const int* __restrict__ pos_ids, const float2* __restrict__ tbl) {
  int i = blockIdx.x * blockDim.x + threadIdx.x;  // bhs*8 + t8
  int t8 = i & 7, bhs = i >> 3;
  int s = bhs & (S_ - 1);
  int b = bhs >> 15;  // NH_*S_ = 32768
  int d0 = t8 * 8;
  int p = pos_ids[b * S_ + s];
  const float2* tp = tbl + p * 64 + d0;
  float cs[8], sn[8];
#pragma unroll
  for (int j = 0; j < 8; ++j) { float2 c2 = tp[j]; cs[j] = c2.x; sn[j] = c2.y; }
  size_t base = (size_t)bhs * HD_ + d0;
  {
    u16x8 x1 = *(const u16x8*)(Qb + base);
    u16x8 x2 = *(const u16x8*)(Qb + base + 64);
    u16x8 o1, o2;
#pragma unroll
    for (int j = 0; j < 8; ++j) {
      float a = bf2f(x1[j]), bb = bf2f(x2[j]);
      o1[j] = f2bf((a * cs[j] - bb * sn[j]) * QSCALE_);
      o2[j] = f2bf((bb * cs[j] + a * sn[j]) * QSCALE_);
    }
    *(u16x8*)(Qb + base) = o1;
    *(u16x8*)(Qb + base + 64) = o2;
  }
  {
    u16x8 x1 = *(const u16x8*)(Kb + base);
    u16x8 x2 = *(const u16x8*)(Kb + base + 64);
    u16x8 o1, o2;
#pragma unroll
    for (int j = 0; j < 8; ++j) {
      float a = bf2f(x1[j]), bb = bf2f(x2[j]);
      o1[j] = f2bf(a * cs[j] - bb * sn[j]);
      o2[j] = f2bf(bb * cs[j] + a * sn[j]);
    }
    *(u16x8*)(Kb + base) = o1;
    *(u16x8*)(Kb + base + 64) = o2;
  }
}

// ---------------- transpose V: (B,S,HID) bf16 -> (B,NH,HD,S) bf16 ----------------
__global__ __launch_bounds__(256)
void transpose_v(const unsigned short* __restrict__ Vin,
                 unsigned short* __restrict__ Vt) {
  __shared__ __align__(16) unsigned short t[64 * 72];
  const int s0 = blockIdx.x * 64, d0 = blockIdx.y * 64, bh = blockIdx.z;
  const int b = bh >> 4, h = bh & 15;
  const int tid = threadIdx.x;
#pragma unroll
  for (int it = 0; it < 2; ++it) {
    int chunk = it * 256 + tid;          // 512 chunks of 8 elems
    int sl = chunk >> 3, dc = (chunk & 7) * 8;
    u16x8 v = *(const u16x8*)&Vin[(size_t)(b * S_ + s0 + sl) * HID_ + h * HD_ + d0 + dc];
    *(u16x8*)&t[sl * 72 + dc] = v;
  }
  __syncthreads();
#pragma unroll
  for (int it = 0; it < 2; ++it) {
    int lin = it * 256 + tid;
    int dl = lin & 63, sq = (lin >> 6) * 8;  // lanes span dl -> banks spread
    u16x8 v;
#pragma unroll
    for (int j = 0; j < 8; ++j) v[j] = t[(sq + j) * 72 + dl];
    *(u16x8*)&Vt[((size_t)bh * HD_ + d0 + dl) * S_ + s0 + sq] = v;
  }
}

// ---------------- fused causal flash attention (v6) ----------------
// v5 -> v6: occupancy 2 -> 3 blocks/CU (LDS 45 KiB x3 = 135 < 160 KiB; VGPR
// capped at 168 by launch bounds). Kernel is latency-bound on the serial
// per-tile chain (QK^T -> shuffle-reduce -> exp -> P LDS roundtrip -> PV);
// +50% TLP is the cheapest lever before a structural 8-warp rewrite.
#define KS_LD 136   // 64x128 K tile, padded (16B-aligned rows, 2-way bank aliasing)
#define VS_LD 72    // 128x64 V^T tile, padded
#define PS_LD 72    // 16x64 P tile per wave, padded (b128-aligned; Ps writes ~4-way)
__global__ __launch_bounds__(256, 3)
void attn_fused(const unsigned short* __restrict__ Qb,
                const unsigned short* __restrict__ Kb,
                const unsigned short* __restrict__ Vt,
                unsigned short* __restrict__ Ob) {
  __shared__ __align__(16) unsigned short Ks[64 * KS_LD];
  __shared__ __align__(16) unsigned short Vts[128 * VS_LD];
  __shared__ __align__(16) unsigned short Ps[4 * 16 * PS_LD];

  const int tid = threadIdx.x, lane = tid & 63, w = tid >> 6;
  const int bh = blockIdx.x;                    // fast dim: spreads heads across XCDs
  const int qt = (gridDim.y - 1) - blockIdx.y;  // descending: longest blocks first (LPT)
  const int q0 = qt * 64;
  const int b = bh >> 4, h = bh & 15;
  const int rowq = lane & 15;
  const int koff = (lane >> 4) * 8;
  const int lr0 = (lane >> 4) * 4;
  const size_t qkbase = (size_t)bh * (S_ * HD_);
  const size_t vbase  = (size_t)bh * (HD_ * S_);

  bf16x8 qf0, qf1, qf2, qf3;
  {
    const unsigned short* qrow = Qb + qkbase + (size_t)(q0 + w * 16 + rowq) * HD_;
    qf0 = *(const bf16x8*)(qrow + 0 * 32 + koff);
    qf1 = *(const bf16x8*)(qrow + 1 * 32 + koff);
    qf2 = *(const bf16x8*)(qrow + 2 * 32 + koff);
    qf3 = *(const bf16x8*)(qrow + 3 * 32 + koff);
  }

  const int krow = tid >> 4, kcol = (tid & 15) * 8;  // K: 16 rows/pass
  const int vrow = tid >> 3, vcol = (tid & 7) * 8;   // V^T: 32 rows/pass
  const unsigned short* kptr = Kb + qkbase + (size_t)krow * HD_ + kcol;
  const unsigned short* vptr = Vt + vbase + (size_t)vrow * S_ + vcol;

  f32x4 oacc[8];
  for (int i = 0; i < 8; ++i)
    for (int r = 0; r < 4; ++r) oacc[i][r] = 0.f;
  float m_r[4] = {-3e38f, -3e38f, -3e38f, -3e38f};
  float l_r[4] = {0.f, 0.f, 0.f, 0.f};

  const int nkt = qt + 1;

  float4 k0, k1, k2, k3, v0, v1, v2, v3;
  k0 = *(const float4*)(kptr + 0 * 16 * HD_);
  k1 = *(const float4*)(kptr + 1 * 16 * HD_);
  k2 = *(const float4*)(kptr + 2 * 16 * HD_);
  k3 = *(const float4*)(kptr + 3 * 16 * HD_);
  v0 = *(const float4*)(vptr + 0 * 32 * S_);
  v1 = *(const float4*)(vptr + 1 * 32 * S_);
  v2 = *(const float4*)(vptr + 2 * 32 * S_);
  v3 = *(const float4*)(vptr + 3 * 32 * S_);

  for (int kt = 0; kt < nkt; ++kt) {
    __syncthreads();  // previous tile's readers done
    *(float4*)&Ks[(krow + 0 * 16) * KS_LD + kcol] = k0;
    *(float4*)&Ks[(krow + 1 * 16) * KS_LD + kcol] = k1;
    *(float4*)&Ks[(krow + 2 * 16) * KS_LD + kcol] = k2;
    *(float4*)&Ks[(krow + 3 * 16) * KS_LD + kcol] = k3;
    *(float4*)&Vts[(vrow + 0 * 32) * VS_LD + vcol] = v0;
    *(float4*)&Vts[(vrow + 1 * 32) * VS_LD + vcol] = v1;
    *(float4*)&Vts[(vrow + 2 * 32) * VS_LD + vcol] = v2;
    *(float4*)&Vts[(vrow + 3 * 32) * VS_LD + vcol] = v3;
    if (kt + 1 < nkt) {
      const unsigned short* kp = kptr + (size_t)(kt + 1) * 64 * HD_;
      k0 = *(const float4*)(kp + 0 * 16 * HD_);
      k1 = *(const float4*)(kp + 1 * 16 * HD_);
      k2 = *(const float4*)(kp + 2 * 16 * HD_);
      k3 = *(const float4*)(kp + 3 * 16 * HD_);
    }
    __syncthreads();

    f32x4 sacc[4];
    for (int n = 0; n < 4; ++n)
      for (int r = 0; r < 4; ++r) sacc[n][r] = 0.f;
#pragma unroll
    for (int n = 0; n < 4; ++n) {
      const unsigned short* krow_p = &Ks[(n * 16 + rowq) * KS_LD + koff];
      sacc[n] = __builtin_amdgcn_mfma_f32_16x16x32_bf16(qf0, *(const bf16x8*)(krow_p + 0 * 32), sacc[n], 0, 0, 0);
      sacc[n] = __builtin_amdgcn_mfma_f32_16x16x32_bf16(qf1, *(const bf16x8*)(krow_p + 1 * 32), sacc[n], 0, 0, 0);
      sacc[n] = __builtin_amdgcn_mfma_f32_16x16x32_bf16(qf2, *(const bf16x8*)(krow_p + 2 * 32), sacc[n], 0, 0, 0);
      sacc[n] = __builtin_amdgcn_mfma_f32_16x16x32_bf16(qf3, *(const bf16x8*)(krow_p + 3 * 32), sacc[n], 0, 0, 0);
    }

    float tmax[4] = {-3e38f, -3e38f, -3e38f, -3e38f};
    if (kt == qt) {
      for (int n = 0; n < 4; ++n) {
        int col = n * 16 + rowq;
        for (int r = 0; r < 4; ++r) {
          int row = w * 16 + lr0 + r;
          float x = (col <= row) ? sacc[n][r] : -1e30f;
          sacc[n][r] = x;
          tmax[r] = fmaxf(tmax[r], x);
        }
      }
    } else {
      for (int n = 0; n < 4; ++n)
        for (int r = 0; r < 4; ++r)
          tmax[r] = fmaxf(tmax[r], sacc[n][r]);
    }
    for (int off = 1; off < 16; off <<= 1)
      for (int r = 0; r < 4; ++r) tmax[r] = fmaxf(tmax[r], __shfl_xor(tmax[r], off));
    float alpha[4];
    for (int r = 0; r < 4; ++r) {
      float mn = fmaxf(m_r[r], tmax[r]);
      alpha[r] = __builtin_amdgcn_exp2f(m_r[r] - mn);
      m_r[r] = mn;
    }
    float rs[4] = {0.f, 0.f, 0.f, 0.f};
    for (int n = 0; n < 4; ++n)
      for (int r = 0; r < 4; ++r) {
        float p = __builtin_amdgcn_exp2f(sacc[n][r] - m_r[r]);
        sacc[n][r] = p;
        rs[r] += p;
      }
    for (int off = 1; off < 16; off <<= 1)
      for (int r = 0; r < 4; ++r) rs[r] += __shfl_xor(rs[r], off);
    for (int r = 0; r < 4; ++r) l_r[r] = l_r[r] * alpha[r] + rs[r];
    for (int nd = 0; nd < 8; ++nd)
      for (int r = 0; r < 4; ++r) oacc[nd][r] *= alpha[r];

    if (kt + 1 < nkt) {
      const unsigned short* vp = vptr + (size_t)(kt + 1) * 64;
      v0 = *(const float4*)(vp + 0 * 32 * S_);
      v1 = *(const float4*)(vp + 1 * 32 * S_);
      v2 = *(const float4*)(vp + 2 * 32 * S_);
      v3 = *(const float4*)(vp + 3 * 32 * S_);
    }

    unsigned short* pw = &Ps[w * 16 * PS_LD];
    for (int n = 0; n < 4; ++n)
      for (int r = 0; r < 4; ++r)
        pw[(lr0 + r) * PS_LD + n * 16 + rowq] = f2bf(sacc[n][r]);

#pragma unroll
    for (int t2 = 0; t2 < 2; ++t2) {
      bf16x8 pa = *(const bf16x8*)&pw[rowq * PS_LD + t2 * 32 + koff];
      for (int nd = 0; nd < 8; ++nd) {
        bf16x8 vb = *(const bf16x8*)&Vts[(nd * 16 + rowq) * VS_LD + t2 * 32 + koff];
        oacc[nd] = __builtin_amdgcn_mfma_f32_16x16x32_bf16(pa, vb, oacc[nd], 0, 0, 0);
      }
    }
  }

  float linv[4];
  for (int r = 0; r < 4; ++r) linv[r] = __builtin_amdgcn_rcpf(l_r[r]);
  for (int nd = 0; nd < 8; ++nd) {
    int col = h * HD_ + nd * 16 + rowq;
    for (int r = 0; r < 4; ++r) {
      int row = q0 + w * 16 + lr0 + r;
      Ob[(size_t)(b * S_ + row) * HID_ + col] = f2bf(oacc[nd][r] * linv[r]);
    }
  }
}

// ---------------- launcher ----------------
extern "C" void kernel_launch(void* const* d_in, const int* in_sizes, int n_in,
                              void* d_out, int out_size, void* d_ws, size_t ws_size,
                              hipStream_t stream) {
  (void)in_sizes; (void)n_in; (void)out_size; (void)ws_size;
  const float* hidden = (const float*)d_in[0];
  // d_in[1] = attention_mask (causal; reproduced analytically)
  const int* pos = (const int*)d_in[2];
  const float* Wq = (const float*)d_in[3];
  const float* Wk = (const float*)d_in[4];
  const float* Wv = (const float*)d_in[5];
  const float* Wo = (const float*)d_in[6];
  float* out = (float*)d_out;

  char* ws = (char*)d_ws;
  unsigned short* Xb   = (unsigned short*)(ws);               // 16 MB  (B,S,HID) bf16
  unsigned short* Wqb  = (unsigned short*)(ws + 16777216);    // 8 MB  Wq -- Wqb/Wkb/Wvb contiguous:
  unsigned short* Wkb  = (unsigned short*)(ws + 25165824);    // 8 MB  Wk -- one (6144,2048) QKV weight
  unsigned short* Wvb  = (unsigned short*)(ws + 33554432);    // 8 MB  Wv
  unsigned short* Wob  = (unsigned short*)(ws + 41943040);    // 8 MB
  unsigned short* Qb   = (unsigned short*)(ws + 50331648);    // 16 MB (B,NH,S,HD)
  unsigned short* Kb   = (unsigned short*)(ws + 67108864);    // 16 MB
  unsigned short* Vtmp = (unsigned short*)(ws + 83886080);    // 16 MB (B,S,HID)
  unsigned short* Vtb  = (unsigned short*)(ws + 100663296);   // 16 MB (B,NH,HD,S)
  unsigned short* Ob   = Xb;          // Xb dead after QKV GEMM
  float2* tbl          = (float2*)ws; // RoPE table also lives in dead Xb region (1 MB)

  cast_all<<<2048, 256, 0, stream>>>(hidden, Wq, Wk, Wv, Wo, Xb, Wqb, Wkb, Wvb, Wob);

  // fused QKV: C (4096 x 6144) = X (4096x2048) * Wqkv^T, 256x192 tiles
  dim3 gq(3 * HID_ / 192, (B_ * S_) / 256);  // (32, 16) = 512 blocks = exactly 2 rounds
  gemm_qkv<<<gq, 512, 0, stream>>>(Xb, Wqb, Qb, Kb, Vtmp);

  rope_table<<<(MAXTOK_ * 64) / 256, 256, 0, stream>>>(tbl);
  rope_apply<<<(B_ * NH_ * S_ * 8) / 256, 256, 0, stream>>>(Qb, Kb, pos, tbl);

  dim3 tg(S_ / 64, HD_ / 64, B_ * NH_);  // (32, 2, 32)
  transpose_v<<<tg, 256, 0, stream>>>(Vtmp, Vtb);

  dim3 ag(B_ * NH_, S_ / 64);  // bh fast, qt slow (descending inside kernel)
  attn_fused<<<ag, 256, 0, stream>>>(Qb, Kb, Vtb, Ob);

  dim3 go(HID_ / 128, (B_ * S_) / 256);  // (16, 16) = 256 blocks = exactly 1 round
  gemm_out<<<go, 512, 0, stream>>>(Ob, Wob, out);
}